// Round 2
// baseline (9974.789 us; speedup 1.0000x reference)
//
#include <hip/hip_runtime.h>
#include <stdint.h>

// Problem constants
#define HDIM 1024
#define NB   512
#define SEQ  128
#define VOUT 4096
#define TSTEPS 32

// Output layout (float elements, concatenated in reference return order)
#define SEQ_OFF 0
#define LP_OFF  16896   // 512*33
#define ENT_OFF 33792   // 2*512*33
#define WS_OFF  50688   // 3*512*33

// ---------------------------------------------------------------- init
__global__ void init_kernel(float* __restrict__ h, int* __restrict__ tok,
                            float* __restrict__ out) {
  int idx = blockIdx.x * blockDim.x + threadIdx.x;   // 2048*256 = 524288 = NB*HDIM
  h[idx] = 0.f;
  if (idx < NB) {
    tok[idx] = VOUT + 2;                             // SOS token
    out[SEQ_OFF + idx * 33 + 32] = 0.f;              // zero tail column
    out[LP_OFF  + idx * 33 + 32] = 0.f;
    out[ENT_OFF + idx * 33 + 32] = 0.f;
  }
}

// ---------------------------------------------------------------- GEMM
// C[M,N] = A(rows maybe gathered)[M,1024] @ W[N,1024]^T + bias
// BM=64, BN=128, BK=32, 256 threads (16x16), 4x8 micro-tile (two 4x4 col quadrants)
__device__ __forceinline__ void gemm_body(
    const float* __restrict__ A, const float* __restrict__ W,
    const float* __restrict__ bias, float* __restrict__ C,
    const int* __restrict__ gidx, int N, int bx, int by) {
  __shared__ __align__(16) float Als[32][68];
  __shared__ __align__(16) float Bls[32][132];
  const int tid = threadIdx.x;
  const int tx = tid & 15, ty = tid >> 4;
  const int m0 = by * 64, n0 = bx * 128;
  const int sr = tid >> 3;          // 0..31
  const int scol = (tid & 7) << 2;  // 0..28

  int r0 = m0 + sr, r1 = m0 + sr + 32;
  if (gidx) { r0 = gidx[r0]; r1 = gidx[r1]; }
  const float* a0 = A + (size_t)r0 * HDIM + scol;
  const float* a1 = A + (size_t)r1 * HDIM + scol;
  const float* w0 = W + (size_t)(n0 + sr) * HDIM + scol;
  const size_t wstep = (size_t)32 * HDIM;

  float accT[4][8];
#pragma unroll
  for (int i = 0; i < 4; ++i)
#pragma unroll
    for (int j = 0; j < 8; ++j) accT[i][j] = 0.f;

  for (int k0 = 0; k0 < HDIM; k0 += 32) {
    float4 av0 = *(const float4*)(a0 + k0);
    float4 av1 = *(const float4*)(a1 + k0);
    float4 wv0 = *(const float4*)(w0 + k0);
    float4 wv1 = *(const float4*)(w0 + wstep + k0);
    float4 wv2 = *(const float4*)(w0 + 2 * wstep + k0);
    float4 wv3 = *(const float4*)(w0 + 3 * wstep + k0);
    __syncthreads();  // previous-iteration consumers done
    Als[scol + 0][sr] = av0.x; Als[scol + 1][sr] = av0.y;
    Als[scol + 2][sr] = av0.z; Als[scol + 3][sr] = av0.w;
    Als[scol + 0][sr + 32] = av1.x; Als[scol + 1][sr + 32] = av1.y;
    Als[scol + 2][sr + 32] = av1.z; Als[scol + 3][sr + 32] = av1.w;
    Bls[scol + 0][sr] = wv0.x; Bls[scol + 1][sr] = wv0.y;
    Bls[scol + 2][sr] = wv0.z; Bls[scol + 3][sr] = wv0.w;
    Bls[scol + 0][sr + 32] = wv1.x; Bls[scol + 1][sr + 32] = wv1.y;
    Bls[scol + 2][sr + 32] = wv1.z; Bls[scol + 3][sr + 32] = wv1.w;
    Bls[scol + 0][sr + 64] = wv2.x; Bls[scol + 1][sr + 64] = wv2.y;
    Bls[scol + 2][sr + 64] = wv2.z; Bls[scol + 3][sr + 64] = wv2.w;
    Bls[scol + 0][sr + 96] = wv3.x; Bls[scol + 1][sr + 96] = wv3.y;
    Bls[scol + 2][sr + 96] = wv3.z; Bls[scol + 3][sr + 96] = wv3.w;
    __syncthreads();

    // chunk accumulator (flushed to accT each BK) for accuracy (~5 eps rel)
    float ac[4][8];
#pragma unroll
    for (int i = 0; i < 4; ++i)
#pragma unroll
      for (int j = 0; j < 8; ++j) ac[i][j] = 0.f;

#pragma unroll
    for (int kk = 0; kk < 32; ++kk) {
      float4 a4 = *(const float4*)&Als[kk][ty * 4];
      float4 b0 = *(const float4*)&Bls[kk][tx * 4];
      float4 b1 = *(const float4*)&Bls[kk][64 + tx * 4];
      float a_[4] = {a4.x, a4.y, a4.z, a4.w};
      float b_[8] = {b0.x, b0.y, b0.z, b0.w, b1.x, b1.y, b1.z, b1.w};
#pragma unroll
      for (int i = 0; i < 4; ++i)
#pragma unroll
        for (int j = 0; j < 8; ++j) ac[i][j] = fmaf(a_[i], b_[j], ac[i][j]);
    }
#pragma unroll
    for (int i = 0; i < 4; ++i)
#pragma unroll
      for (int j = 0; j < 8; ++j) accT[i][j] += ac[i][j];
  }

#pragma unroll
  for (int i = 0; i < 4; ++i) {
    int m = m0 + ty * 4 + i;
    float4 o0, o1;
    o0.x = accT[i][0] + bias[n0 + tx * 4 + 0];
    o0.y = accT[i][1] + bias[n0 + tx * 4 + 1];
    o0.z = accT[i][2] + bias[n0 + tx * 4 + 2];
    o0.w = accT[i][3] + bias[n0 + tx * 4 + 3];
    o1.x = accT[i][4] + bias[n0 + 64 + tx * 4 + 0];
    o1.y = accT[i][5] + bias[n0 + 64 + tx * 4 + 1];
    o1.z = accT[i][6] + bias[n0 + 64 + tx * 4 + 2];
    o1.w = accT[i][7] + bias[n0 + 64 + tx * 4 + 3];
    *(float4*)&C[(size_t)m * N + n0 + tx * 4] = o0;
    *(float4*)&C[(size_t)m * N + n0 + 64 + tx * 4] = o1;
  }
}

// z=0: gi = emb[tok] @ W_ih^T + b_ih ; z=1: gh = h @ W_hh^T + b_hh
__global__ __launch_bounds__(256) void gemm_gru_kernel(
    const float* __restrict__ emb, const float* __restrict__ W_ih,
    const float* __restrict__ b_ih, float* __restrict__ gi,
    const float* __restrict__ h, const float* __restrict__ W_hh,
    const float* __restrict__ b_hh, float* __restrict__ gh,
    const int* __restrict__ tok) {
  if (blockIdx.z == 0)
    gemm_body(emb, W_ih, b_ih, gi, tok, 3 * HDIM, blockIdx.x, blockIdx.y);
  else
    gemm_body(h, W_hh, b_hh, gh, nullptr, 3 * HDIM, blockIdx.x, blockIdx.y);
}

__global__ __launch_bounds__(256) void gemm_logits_kernel(
    const float* __restrict__ x, const float* __restrict__ W_out,
    const float* __restrict__ b_out, float* __restrict__ logits) {
  gemm_body(x, W_out, b_out, logits, nullptr, VOUT, blockIdx.x, blockIdx.y);
}

// ---------------------------------------------------------------- GRU gate
__global__ __launch_bounds__(256) void gate_kernel(const float* __restrict__ gi,
                                                   const float* __restrict__ gh,
                                                   float* __restrict__ h) {
  int idx = blockIdx.x * blockDim.x + threadIdx.x;  // 131072, one float4 each
  int b = idx >> 8;
  int c = (idx & 255) << 2;
  const size_t g0 = (size_t)b * 3 * HDIM + c;
  float4 ir = *(const float4*)&gi[g0];
  float4 iz = *(const float4*)&gi[g0 + HDIM];
  float4 in_ = *(const float4*)&gi[g0 + 2 * HDIM];
  float4 hr = *(const float4*)&gh[g0];
  float4 hz = *(const float4*)&gh[g0 + HDIM];
  float4 hn = *(const float4*)&gh[g0 + 2 * HDIM];
  float4 hv = *(const float4*)&h[(size_t)b * HDIM + c];
  float4 o;
  {
    float r = 1.f / (1.f + expf(-(ir.x + hr.x)));
    float z = 1.f / (1.f + expf(-(iz.x + hz.x)));
    float n = tanhf(in_.x + r * hn.x);
    o.x = (1.f - z) * n + z * hv.x;
  }
  {
    float r = 1.f / (1.f + expf(-(ir.y + hr.y)));
    float z = 1.f / (1.f + expf(-(iz.y + hz.y)));
    float n = tanhf(in_.y + r * hn.y);
    o.y = (1.f - z) * n + z * hv.y;
  }
  {
    float r = 1.f / (1.f + expf(-(ir.z + hr.z)));
    float z = 1.f / (1.f + expf(-(iz.z + hz.z)));
    float n = tanhf(in_.z + r * hn.z);
    o.z = (1.f - z) * n + z * hv.z;
  }
  {
    float r = 1.f / (1.f + expf(-(ir.w + hr.w)));
    float z = 1.f / (1.f + expf(-(iz.w + hz.w)));
    float n = tanhf(in_.w + r * hn.w);
    o.w = (1.f - z) * n + z * hv.w;
  }
  *(float4*)&h[(size_t)b * HDIM + c] = o;
}

// ---------------------------------------------------------------- attention
// scores = (h . K)/32 -> softmax -> ws out (f32); x = w.V + h
__global__ __launch_bounds__(512) void attn_kernel(
    const float* __restrict__ h, const float* __restrict__ enc,
    const float* __restrict__ sem, const float* __restrict__ emb,
    float* __restrict__ x, float* __restrict__ out, int t) {
  const int b = blockIdx.x;
  const int tid = threadIdx.x;
  const int lane = tid & 63, wv = tid >> 6;  // 8 waves
  __shared__ __align__(16) float hs[HDIM];
  __shared__ float scl[132];
  __shared__ float wls[132];
  __shared__ float mred, sred;

  *(float2*)&hs[tid * 2] = *(const float2*)&h[(size_t)b * HDIM + tid * 2];
  __syncthreads();

  for (int k = wv; k < SEQ + 1; k += 8) {
    const float* kr = (k < SEQ) ? (enc + ((size_t)b * SEQ + k) * HDIM)
                                : (emb + (size_t)VOUT * HDIM);
    float s = 0.f;
#pragma unroll
    for (int it = 0; it < 4; ++it) {
      float4 kv = *(const float4*)(kr + lane * 4 + it * 256);
      float4 hv = *(const float4*)&hs[lane * 4 + it * 256];
      s += kv.x * hv.x + kv.y * hv.y + kv.z * hv.z + kv.w * hv.w;
    }
#pragma unroll
    for (int off = 32; off; off >>= 1) s += __shfl_xor(s, off);
    if (lane == 0) scl[k] = s * 0.03125f;  // * 1/sqrt(1024)
  }
  __syncthreads();

  if (wv == 0) {  // softmax stats over 129 scores, tree reduce (accurate)
    float va = scl[lane];
    float vb = scl[lane + 64];                       // covers 64..127
    float vc = (lane == 0) ? scl[128] : -3.4e38f;
    float m = fmaxf(fmaxf(va, vb), vc);
#pragma unroll
    for (int off = 32; off; off >>= 1) m = fmaxf(m, __shfl_xor(m, off));
    float e = expf(va - m) + expf(vb - m);
    if (lane == 0) e += expf(vc - m);
#pragma unroll
    for (int off = 32; off; off >>= 1) e += __shfl_xor(e, off);
    if (lane == 0) { mred = m; sred = e; }
  }
  __syncthreads();
  float m = mred, ssum = sred;
  if (tid < SEQ + 1) {
    float w = expf(scl[tid] - m) / ssum;
    wls[tid] = w;
    out[WS_OFF + ((size_t)b * TSTEPS + t) * (SEQ + 1) + tid] = w;
  }
  __syncthreads();

  const int d = tid * 2;
  float r0 = 0.f, r1 = 0.f;
  const float* vb_ = sem + (size_t)b * SEQ * HDIM + d;
  for (int k = 0; k < SEQ; ++k) {
    float2 v = *(const float2*)(vb_ + (size_t)k * HDIM);
    float wk = wls[k];
    r0 = fmaf(wk, v.x, r0);
    r1 = fmaf(wk, v.y, r1);
  }
  {
    float2 v = *(const float2*)(emb + (size_t)(VOUT + 1) * HDIM + d);
    float wk = wls[SEQ];
    r0 = fmaf(wk, v.x, r0);
    r1 = fmaf(wk, v.y, r1);
  }
  float2 xo;
  xo.x = r0 + hs[d];
  xo.y = r1 + hs[d + 1];
  *(float2*)&x[(size_t)b * HDIM + d] = xo;
}

// ---------------------------------------------------------------- finalize
__global__ __launch_bounds__(256) void finalize_kernel(
    const float* __restrict__ logits, float* __restrict__ out,
    int* __restrict__ tok, int t) {
  const int b = blockIdx.x, tid = threadIdx.x;
  const float* lrow = logits + (size_t)b * VOUT;
  float m = -3.4e38f; int mi = 0;
  for (int j = tid; j < VOUT; j += 256) {
    float v = lrow[j];
    if (v > m) { m = v; mi = j; }
  }
  __shared__ float sm[256];
  __shared__ int si[256];
  sm[tid] = m; si[tid] = mi;
  __syncthreads();
  for (int off = 128; off; off >>= 1) {
    if (tid < off) {
      float om = sm[tid + off]; int oi = si[tid + off];
      if (om > sm[tid] || (om == sm[tid] && oi < si[tid])) { sm[tid] = om; si[tid] = oi; }
    }
    __syncthreads();
  }
  m = sm[0]; mi = si[0];

  float s = 0.f, ts = 0.f;
  for (int j = tid; j < VOUT; j += 256) {
    float v = lrow[j];
    float e = expf(v - m);
    s += e;
    ts = fmaf(e, v, ts);
  }
#pragma unroll
  for (int off = 32; off; off >>= 1) {
    s += __shfl_xor(s, off);
    ts += __shfl_xor(ts, off);
  }
  __shared__ float ssum[4], tsum[4];
  if ((tid & 63) == 0) { ssum[tid >> 6] = s; tsum[tid >> 6] = ts; }
  __syncthreads();
  if (tid == 0) {
    s = ssum[0] + ssum[1] + ssum[2] + ssum[3];
    ts = tsum[0] + tsum[1] + tsum[2] + tsum[3];
    float lse = m + logf(s);
    float lp = m - lse;            // logp at argmax
    float ent = lse - ts / s;      // -sum p*logp
    out[SEQ_OFF + (size_t)b * 33 + t] = (float)mi;
    out[LP_OFF  + (size_t)b * 33 + t] = lp;
    out[ENT_OFF + (size_t)b * 33 + t] = ent;
    tok[b] = mi;
  }
}

// ---------------------------------------------------------------- launch
extern "C" void kernel_launch(void* const* d_in, const int* in_sizes, int n_in,
                              void* d_out, int out_size, void* d_ws, size_t ws_size,
                              hipStream_t stream) {
  const float* enc   = (const float*)d_in[0];
  const float* sem   = (const float*)d_in[1];
  const float* emb   = (const float*)d_in[2];
  const float* W_ih  = (const float*)d_in[3];
  const float* W_hh  = (const float*)d_in[4];
  const float* b_ih  = (const float*)d_in[5];
  const float* b_hh  = (const float*)d_in[6];
  const float* W_out = (const float*)d_in[7];
  const float* b_out = (const float*)d_in[8];
  float* out = (float*)d_out;

  float* h      = (float*)d_ws;                 // 512*1024
  float* x      = h + (size_t)NB * HDIM;        // 512*1024
  float* gi     = x + (size_t)NB * HDIM;        // 512*3072
  float* gh     = gi + (size_t)NB * 3 * HDIM;   // 512*3072
  float* logits = gh + (size_t)NB * 3 * HDIM;   // 512*4096
  int*   tok    = (int*)(logits + (size_t)NB * VOUT);

  init_kernel<<<2048, 256, 0, stream>>>(h, tok, out);

  for (int t = 0; t < TSTEPS; ++t) {
    dim3 g1(24, 8, 2);  // N=3072/128, M=512/64, {gi, gh}
    gemm_gru_kernel<<<g1, 256, 0, stream>>>(emb, W_ih, b_ih, gi, h, W_hh, b_hh, gh, tok);
    gate_kernel<<<512, 256, 0, stream>>>(gi, gh, h);
    attn_kernel<<<512, 512, 0, stream>>>(h, enc, sem, emb, x, out, t);
    dim3 g2(32, 8, 1);  // N=4096/128, M=512/64
    gemm_logits_kernel<<<g2, 256, 0, stream>>>(x, W_out, b_out, logits);
    finalize_kernel<<<512, 256, 0, stream>>>(logits, out, tok, t);
  }
}

// Round 3
// 7871.323 us; speedup vs baseline: 1.2672x; 1.2672x over previous
//
#include <hip/hip_runtime.h>
#include <stdint.h>

// Problem constants
#define HDIM 1024
#define NB   512
#define SEQ  128
#define VOUT 4096
#define TSTEPS 32
#define EROWS 4160   // padded E2 rows (4099 valid, rest garbage-but-deterministic)

// Output layout (float elements, concatenated in reference return order)
#define SEQ_OFF 0
#define LP_OFF  16896   // 512*33
#define ENT_OFF 33792   // 2*512*33
#define WS_OFF  50688   // 3*512*33

// ---------------------------------------------------------------- init
__global__ void init_kernel(float* __restrict__ h, int* __restrict__ tok,
                            float* __restrict__ out) {
  int idx = blockIdx.x * blockDim.x + threadIdx.x;   // 2048*256 = NB*HDIM
  h[idx] = 0.f;
  if (idx < NB) {
    tok[idx] = VOUT + 2;                             // SOS token
    out[SEQ_OFF + idx * 33 + 32] = 0.f;              // zero tail column
    out[LP_OFF  + idx * 33 + 32] = 0.f;
    out[ENT_OFF + idx * 33 + 32] = 0.f;
  }
}

// ---------------------------------------------------------------- GEMM64
// C[M,N] = A[M,1024] @ W[N,1024]^T + bias.  BM=BN=64, BK=32, 256 thr, 4x4 micro.
// Row loads clamped to Mlim-1 (for the 4160-padded E2 precompute).
__global__ __launch_bounds__(256) void gemm64_kernel(
    const float* __restrict__ A, const float* __restrict__ W,
    const float* __restrict__ bias, float* __restrict__ C,
    int N, int Mlim) {
  __shared__ __align__(16) float Als[32][68];
  __shared__ __align__(16) float Bls[32][68];
  const int tid = threadIdx.x;
  const int tx = tid & 15, ty = tid >> 4;
  const int m0 = blockIdx.y * 64, n0 = blockIdx.x * 64;
  const int sr = tid >> 3;          // 0..31
  const int scol = (tid & 7) << 2;  // 0..28

  const int ra = min(m0 + sr, Mlim - 1);
  const int rb = min(m0 + sr + 32, Mlim - 1);
  const float* a0 = A + (size_t)ra * HDIM + scol;
  const float* a1 = A + (size_t)rb * HDIM + scol;
  const float* w0 = W + (size_t)(n0 + sr) * HDIM + scol;
  const float* w1 = W + (size_t)(n0 + sr + 32) * HDIM + scol;

  float accT[4][4];
#pragma unroll
  for (int i = 0; i < 4; ++i)
#pragma unroll
    for (int j = 0; j < 4; ++j) accT[i][j] = 0.f;

  for (int k0 = 0; k0 < HDIM; k0 += 32) {
    float4 av0 = *(const float4*)(a0 + k0);
    float4 av1 = *(const float4*)(a1 + k0);
    float4 wv0 = *(const float4*)(w0 + k0);
    float4 wv1 = *(const float4*)(w1 + k0);
    __syncthreads();  // previous-iteration consumers done
    Als[scol + 0][sr] = av0.x; Als[scol + 1][sr] = av0.y;
    Als[scol + 2][sr] = av0.z; Als[scol + 3][sr] = av0.w;
    Als[scol + 0][sr + 32] = av1.x; Als[scol + 1][sr + 32] = av1.y;
    Als[scol + 2][sr + 32] = av1.z; Als[scol + 3][sr + 32] = av1.w;
    Bls[scol + 0][sr] = wv0.x; Bls[scol + 1][sr] = wv0.y;
    Bls[scol + 2][sr] = wv0.z; Bls[scol + 3][sr] = wv0.w;
    Bls[scol + 0][sr + 32] = wv1.x; Bls[scol + 1][sr + 32] = wv1.y;
    Bls[scol + 2][sr + 32] = wv1.z; Bls[scol + 3][sr + 32] = wv1.w;
    __syncthreads();

    // chunk accumulator (flushed per BK) keeps error ~5 eps
    float ac[4][4];
#pragma unroll
    for (int i = 0; i < 4; ++i)
#pragma unroll
      for (int j = 0; j < 4; ++j) ac[i][j] = 0.f;

#pragma unroll
    for (int kk = 0; kk < 32; ++kk) {
      float4 a4 = *(const float4*)&Als[kk][ty * 4];
      float4 b4 = *(const float4*)&Bls[kk][tx * 4];
      float a_[4] = {a4.x, a4.y, a4.z, a4.w};
      float b_[4] = {b4.x, b4.y, b4.z, b4.w};
#pragma unroll
      for (int i = 0; i < 4; ++i)
#pragma unroll
        for (int j = 0; j < 4; ++j) ac[i][j] = fmaf(a_[i], b_[j], ac[i][j]);
    }
#pragma unroll
    for (int i = 0; i < 4; ++i)
#pragma unroll
      for (int j = 0; j < 4; ++j) accT[i][j] += ac[i][j];
  }

#pragma unroll
  for (int i = 0; i < 4; ++i) {
    int m = m0 + ty * 4 + i;
    float4 o;
    o.x = accT[i][0] + bias[n0 + tx * 4 + 0];
    o.y = accT[i][1] + bias[n0 + tx * 4 + 1];
    o.z = accT[i][2] + bias[n0 + tx * 4 + 2];
    o.w = accT[i][3] + bias[n0 + tx * 4 + 3];
    *(float4*)&C[(size_t)m * N + n0 + tx * 4] = o;
  }
}

// ---------------------------------------------------------------- GRU gate
// gi = E2[tok[b]] (precomputed emb@W_ih^T + b_ih); gh from gemm (incl. b_hh)
__global__ __launch_bounds__(256) void gate_kernel(
    const float* __restrict__ E2, const float* __restrict__ gh,
    const int* __restrict__ tok, float* __restrict__ h) {
  int idx = blockIdx.x * blockDim.x + threadIdx.x;  // 131072, one float4 each
  int b = idx >> 8;
  int c = (idx & 255) << 2;
  const float* e = E2 + (size_t)tok[b] * (3 * HDIM) + c;
  const float* g = gh + (size_t)b * (3 * HDIM) + c;
  float4 ir = *(const float4*)(e);
  float4 iz = *(const float4*)(e + HDIM);
  float4 in_ = *(const float4*)(e + 2 * HDIM);
  float4 hr = *(const float4*)(g);
  float4 hz = *(const float4*)(g + HDIM);
  float4 hn = *(const float4*)(g + 2 * HDIM);
  float4 hv = *(const float4*)&h[(size_t)b * HDIM + c];
  float4 o;
  {
    float r = 1.f / (1.f + expf(-(ir.x + hr.x)));
    float z = 1.f / (1.f + expf(-(iz.x + hz.x)));
    float n = tanhf(in_.x + r * hn.x);
    o.x = (1.f - z) * n + z * hv.x;
  }
  {
    float r = 1.f / (1.f + expf(-(ir.y + hr.y)));
    float z = 1.f / (1.f + expf(-(iz.y + hz.y)));
    float n = tanhf(in_.y + r * hn.y);
    o.y = (1.f - z) * n + z * hv.y;
  }
  {
    float r = 1.f / (1.f + expf(-(ir.z + hr.z)));
    float z = 1.f / (1.f + expf(-(iz.z + hz.z)));
    float n = tanhf(in_.z + r * hn.z);
    o.z = (1.f - z) * n + z * hv.z;
  }
  {
    float r = 1.f / (1.f + expf(-(ir.w + hr.w)));
    float z = 1.f / (1.f + expf(-(iz.w + hz.w)));
    float n = tanhf(in_.w + r * hn.w);
    o.w = (1.f - z) * n + z * hv.w;
  }
  *(float4*)&h[(size_t)b * HDIM + c] = o;
}

// ---------------------------------------------------------------- attention (fused)
// One pass: per k, u_k = exp(score_k) (no max-subtract; |s|<~6 safe in f32),
// acc += u_k * v_k. Normalize by 1/sum(u) at the end. 16 waves, 1 block per b.
__global__ __launch_bounds__(1024) void attn_kernel(
    const float* __restrict__ h, const float* __restrict__ enc,
    const float* __restrict__ sem, const float* __restrict__ emb,
    float* __restrict__ x, float* __restrict__ out, int t) {
  const int b = blockIdx.x;
  const int tid = threadIdx.x;
  const int lane = tid & 63, wv = tid >> 6;  // 16 waves
  __shared__ __align__(16) float hs[HDIM];
  __shared__ float uls[132];
  __shared__ float usums[16];
  __shared__ __align__(16) float accb[16][HDIM];

  hs[tid] = h[(size_t)b * HDIM + tid];
  __syncthreads();

  const int l4 = lane * 4;
  // h fragments are loop-invariant: hoist to registers (no LDS in hot loop)
  float4 hv0 = *(const float4*)&hs[l4];
  float4 hv1 = *(const float4*)&hs[l4 + 256];
  float4 hv2 = *(const float4*)&hs[l4 + 512];
  float4 hv3 = *(const float4*)&hs[l4 + 768];

  float4 acc0 = {0, 0, 0, 0}, acc1 = {0, 0, 0, 0};
  float4 acc2 = {0, 0, 0, 0}, acc3 = {0, 0, 0, 0};
  float usum = 0.f;

  for (int k = wv; k < SEQ + 1; k += 16) {
    const float* kr;
    const float* vr;
    if (k < SEQ) {
      kr = enc + ((size_t)b * SEQ + k) * HDIM;
      vr = sem + ((size_t)b * SEQ + k) * HDIM;
    } else {
      kr = emb + (size_t)VOUT * HDIM;
      vr = emb + (size_t)(VOUT + 1) * HDIM;
    }
    float4 e0 = *(const float4*)(kr + l4);
    float4 e1 = *(const float4*)(kr + l4 + 256);
    float4 e2 = *(const float4*)(kr + l4 + 512);
    float4 e3 = *(const float4*)(kr + l4 + 768);
    float4 v0 = *(const float4*)(vr + l4);
    float4 v1 = *(const float4*)(vr + l4 + 256);
    float4 v2 = *(const float4*)(vr + l4 + 512);
    float4 v3 = *(const float4*)(vr + l4 + 768);

    float p = 0.f;
    p = fmaf(e0.x, hv0.x, p); p = fmaf(e0.y, hv0.y, p);
    p = fmaf(e0.z, hv0.z, p); p = fmaf(e0.w, hv0.w, p);
    p = fmaf(e1.x, hv1.x, p); p = fmaf(e1.y, hv1.y, p);
    p = fmaf(e1.z, hv1.z, p); p = fmaf(e1.w, hv1.w, p);
    p = fmaf(e2.x, hv2.x, p); p = fmaf(e2.y, hv2.y, p);
    p = fmaf(e2.z, hv2.z, p); p = fmaf(e2.w, hv2.w, p);
    p = fmaf(e3.x, hv3.x, p); p = fmaf(e3.y, hv3.y, p);
    p = fmaf(e3.z, hv3.z, p); p = fmaf(e3.w, hv3.w, p);
#pragma unroll
    for (int off = 32; off; off >>= 1) p += __shfl_xor(p, off);

    float u = expf(p * 0.03125f);  // * 1/sqrt(1024)
    usum += u;
    if (lane == 0) uls[k] = u;

    acc0.x = fmaf(u, v0.x, acc0.x); acc0.y = fmaf(u, v0.y, acc0.y);
    acc0.z = fmaf(u, v0.z, acc0.z); acc0.w = fmaf(u, v0.w, acc0.w);
    acc1.x = fmaf(u, v1.x, acc1.x); acc1.y = fmaf(u, v1.y, acc1.y);
    acc1.z = fmaf(u, v1.z, acc1.z); acc1.w = fmaf(u, v1.w, acc1.w);
    acc2.x = fmaf(u, v2.x, acc2.x); acc2.y = fmaf(u, v2.y, acc2.y);
    acc2.z = fmaf(u, v2.z, acc2.z); acc2.w = fmaf(u, v2.w, acc2.w);
    acc3.x = fmaf(u, v3.x, acc3.x); acc3.y = fmaf(u, v3.y, acc3.y);
    acc3.z = fmaf(u, v3.z, acc3.z); acc3.w = fmaf(u, v3.w, acc3.w);
  }

  if (lane == 0) usums[wv] = usum;
  *(float4*)&accb[wv][l4] = acc0;
  *(float4*)&accb[wv][l4 + 256] = acc1;
  *(float4*)&accb[wv][l4 + 512] = acc2;
  *(float4*)&accb[wv][l4 + 768] = acc3;
  __syncthreads();

  float U = 0.f;
#pragma unroll
  for (int w = 0; w < 16; ++w) U += usums[w];
  float rinv = 1.f / U;

  float sum = 0.f;
#pragma unroll
  for (int w = 0; w < 16; ++w) sum += accb[w][tid];
  x[(size_t)b * HDIM + tid] = sum * rinv + hs[tid];

  if (tid < SEQ + 1)
    out[WS_OFF + ((size_t)b * TSTEPS + t) * (SEQ + 1) + tid] = uls[tid] * rinv;
}

// ---------------------------------------------------------------- finalize
// Single pass over logits: argmax + sum(exp) + sum(exp*v) (unshifted, safe).
__global__ __launch_bounds__(256) void finalize_kernel(
    const float* __restrict__ logits, float* __restrict__ out,
    int* __restrict__ tok, int t) {
  const int b = blockIdx.x, tid = threadIdx.x;
  const int lane = tid & 63, wv = tid >> 6;
  const float* lrow = logits + (size_t)b * VOUT;
  float m = -3.4e38f; int mi = 0;
  float s = 0.f, ts = 0.f;
#pragma unroll
  for (int it = 0; it < 4; ++it) {
    int j = (tid << 2) + (it << 10);
    float4 v = *(const float4*)&lrow[j];
    float e;
    e = expf(v.x); s += e; ts = fmaf(e, v.x, ts); if (v.x > m) { m = v.x; mi = j; }
    e = expf(v.y); s += e; ts = fmaf(e, v.y, ts); if (v.y > m) { m = v.y; mi = j + 1; }
    e = expf(v.z); s += e; ts = fmaf(e, v.z, ts); if (v.z > m) { m = v.z; mi = j + 2; }
    e = expf(v.w); s += e; ts = fmaf(e, v.w, ts); if (v.w > m) { m = v.w; mi = j + 3; }
  }
#pragma unroll
  for (int off = 32; off; off >>= 1) {
    float om = __shfl_xor(m, off);
    int oi = __shfl_xor(mi, off);
    s += __shfl_xor(s, off);
    ts += __shfl_xor(ts, off);
    if (om > m || (om == m && oi < mi)) { m = om; mi = oi; }
  }
  __shared__ float smx[4], ssm[4], sts[4];
  __shared__ int smi[4];
  if (lane == 0) { smx[wv] = m; smi[wv] = mi; ssm[wv] = s; sts[wv] = ts; }
  __syncthreads();
  if (tid == 0) {
#pragma unroll
    for (int w = 1; w < 4; ++w) {
      s += ssm[w]; ts += sts[w];
      if (smx[w] > m || (smx[w] == m && smi[w] < mi)) { m = smx[w]; mi = smi[w]; }
    }
    float lse = logf(s);
    float lp = m - lse;
    float ent = lse - ts / s;
    out[SEQ_OFF + (size_t)b * 33 + t] = (float)mi;
    out[LP_OFF  + (size_t)b * 33 + t] = lp;
    out[ENT_OFF + (size_t)b * 33 + t] = ent;
    tok[b] = mi;
  }
}

// ---------------------------------------------------------------- launch
extern "C" void kernel_launch(void* const* d_in, const int* in_sizes, int n_in,
                              void* d_out, int out_size, void* d_ws, size_t ws_size,
                              hipStream_t stream) {
  const float* enc   = (const float*)d_in[0];
  const float* sem   = (const float*)d_in[1];
  const float* emb   = (const float*)d_in[2];
  const float* W_ih  = (const float*)d_in[3];
  const float* W_hh  = (const float*)d_in[4];
  const float* b_ih  = (const float*)d_in[5];
  const float* b_hh  = (const float*)d_in[6];
  const float* W_out = (const float*)d_in[7];
  const float* b_out = (const float*)d_in[8];
  float* out = (float*)d_out;

  float* h      = (float*)d_ws;                        // 512*1024
  float* x      = h + (size_t)NB * HDIM;               // 512*1024
  float* gh     = x + (size_t)NB * HDIM;               // 512*3072
  float* logits = gh + (size_t)NB * 3 * HDIM;          // 512*4096
  float* E2     = logits + (size_t)NB * VOUT;          // 4160*3072
  int*   tok    = (int*)(E2 + (size_t)EROWS * 3 * HDIM);

  init_kernel<<<2048, 256, 0, stream>>>(h, tok, out);
  // E2 = embedding @ W_ih^T + b_ih  (once per launch; rows clamped at 4099)
  gemm64_kernel<<<dim3(48, 65), 256, 0, stream>>>(emb, W_ih, b_ih, E2,
                                                  3 * HDIM, VOUT + 3);

  for (int t = 0; t < TSTEPS; ++t) {
    gemm64_kernel<<<dim3(48, 8), 256, 0, stream>>>(h, W_hh, b_hh, gh,
                                                   3 * HDIM, NB);
    gate_kernel<<<512, 256, 0, stream>>>(E2, gh, tok, h);
    attn_kernel<<<512, 1024, 0, stream>>>(h, enc, sem, emb, x, out, t);
    gemm64_kernel<<<dim3(64, 8), 256, 0, stream>>>(x, W_out, b_out, logits,
                                                   VOUT, NB);
    finalize_kernel<<<512, 256, 0, stream>>>(logits, out, tok, t);
  }
}